// Round 2
// baseline (745.205 us; speedup 1.0000x reference)
//
#include <hip/hip_runtime.h>

#define B_  4
#define C_  64
#define OC_ 64
#define H_  256
#define W_  256
#define HW_ 65536
#define NPIX_ (B_*HW_)        /* 262144 */
#define NELEM_ (B_*C_*HW_)    /* 16777216 */

// ---------------- K1: depthwise 3x3 conv (cross-correlation, zero pad=1) ----
__global__ __launch_bounds__(256) void k_dwconv(
    const float* __restrict__ x,
    const float* __restrict__ dw,
    float* __restrict__ t)
{
  int idx = blockIdx.x*256 + threadIdx.x;        // over B*C*H*W
  int w  = idx & (W_-1);
  int h  = (idx >> 8) & (H_-1);
  int bc = idx >> 16;                            // b*64 + c
  int c  = bc & (C_-1);
  const float* xp = x + (size_t)bc*HW_;
  const float* wp = dw + c*9;
  float acc = 0.f;
#pragma unroll
  for (int i=0;i<3;i++){
    int hy = h + i - 1;
    if ((unsigned)hy >= (unsigned)H_) continue;
#pragma unroll
    for (int j=0;j<3;j++){
      int wx = w + j - 1;
      if ((unsigned)wx >= (unsigned)W_) continue;
      acc += wp[i*3+j] * xp[hy*W_+wx];
    }
  }
  t[idx] = acc;
}

// ---------------- K2: fused pw-conv(64->192) + deformable sample + out-GEMM -
// Channel mapping trap: offset.reshape(B,C,2,H,W) interleaves the concatenated
// [offset_y, offset_x] block, so for sample-channel c: sy uses om[2c], sx uses
// om[2c+1], modulator uses om[128+c].
// Bias is omitted: BN subtracts the mean, so a per-channel bias cancels exactly.
__global__ __launch_bounds__(256) void k_fused(
    const float* __restrict__ x,
    const float* __restrict__ t,
    const float* __restrict__ pw,
    const float* __restrict__ w2,
    float* __restrict__ outF)
{
  int tid = threadIdx.x;
  int gp = blockIdx.x*256 + tid;                 // global pixel id
  int b = gp >> 16;
  int p = gp & (HW_-1);
  int h = p >> 8;
  int w = p & (W_-1);

  float tv[64];
  const float* tb = t + (size_t)(b*C_)*HW_ + p;
#pragma unroll
  for (int c=0;c<64;c++) tv[c] = tb[(size_t)c*HW_];

  const float* xb = x + (size_t)(b*C_)*HW_;

  float sval[64];

  for (int c=0;c<64;c++){
    // pw rows 2c (y-offset), 2c+1 (x-offset), 128+c (modulator); uniform addrs
    const float4* q0 = (const float4*)(pw + (2*c  )*64);
    const float4* q1 = (const float4*)(pw + (2*c+1)*64);
    const float4* q2 = (const float4*)(pw + (128+c)*64);
    float oy=0.f, ox=0.f, mm=0.f;
#pragma unroll
    for (int j=0;j<16;j++){
      float4 a = q0[j]; float4 e = q1[j]; float4 d = q2[j];
      oy += a.x*tv[4*j+0] + a.y*tv[4*j+1] + a.z*tv[4*j+2] + a.w*tv[4*j+3];
      ox += e.x*tv[4*j+0] + e.y*tv[4*j+1] + e.z*tv[4*j+2] + e.w*tv[4*j+3];
      mm += d.x*tv[4*j+0] + d.y*tv[4*j+1] + d.z*tv[4*j+2] + d.w*tv[4*j+3];
    }
    float mod = 2.f / (1.f + __expf(-mm));
    oy = fminf(fmaxf(oy, -64.f), 64.f);          // max_off = 256//4
    ox = fminf(fmaxf(ox, -64.f), 64.f);
    float sy = (float)h + oy;
    float sx = (float)w + ox;
    float y0f = floorf(sy), x0f = floorf(sx);
    float wy = sy - y0f, wx = sx - x0f;
    int y0 = (int)y0f, x0 = (int)x0f;
    const float* xc = xb + (size_t)c*HW_;
    float v00=0.f, v01=0.f, v10=0.f, v11=0.f;
    bool y0v = ((unsigned)y0     < (unsigned)H_);
    bool y1v = ((unsigned)(y0+1) < (unsigned)H_);
    bool x0v = ((unsigned)x0     < (unsigned)W_);
    bool x1v = ((unsigned)(x0+1) < (unsigned)W_);
    int base0 = y0*W_ + x0;
    if (y0v && x0v) v00 = xc[base0];
    if (y0v && x1v) v01 = xc[base0+1];
    if (y1v && x0v) v10 = xc[base0+W_];
    if (y1v && x1v) v11 = xc[base0+W_+1];
    float sres = (1.f-wy)*((1.f-wx)*v00 + wx*v01) + wy*((1.f-wx)*v10 + wx*v11);
    sval[c] = sres * mod;
  }

  // out-GEMM: out[o] = sum_c w2[o][c]*sval[c]; w2 rows contiguous, uniform addrs
  float* op = outF + (size_t)(b*OC_)*HW_ + p;
  for (int o=0;o<64;o++){
    const float4* wr = (const float4*)(w2 + o*64);
    float acc = 0.f;
#pragma unroll
    for (int j=0;j<16;j++){
      float4 wv = wr[j];
      acc += wv.x*sval[4*j+0] + wv.y*sval[4*j+1] + wv.z*sval[4*j+2] + wv.w*sval[4*j+3];
    }
    op[(size_t)o*HW_] = acc;
  }
}

// ---------------- K3: per-channel sum / sumsq over outF ----------------------
__global__ __launch_bounds__(256) void k_stats(
    const float4* __restrict__ outF4,
    float* __restrict__ gsum,
    float* __restrict__ gsq)
{
  __shared__ float ps1[4], ps2[4];
  int i = blockIdx.x*256 + threadIdx.x;          // over NELEM_/4
  float4 v = outF4[i];
  float s1 = v.x + v.y + v.z + v.w;
  float s2 = v.x*v.x + v.y*v.y + v.z*v.z + v.w*v.w;
#pragma unroll
  for (int m=32;m>0;m>>=1){
    s1 += __shfl_xor(s1, m, 64);
    s2 += __shfl_xor(s2, m, 64);
  }
  int wave = threadIdx.x >> 6, lane = threadIdx.x & 63;
  if (lane == 0){ ps1[wave] = s1; ps2[wave] = s2; }
  __syncthreads();
  if (threadIdx.x == 0){
    float t1 = ps1[0]+ps1[1]+ps1[2]+ps1[3];
    float t2 = ps2[0]+ps2[1]+ps2[2]+ps2[3];
    // block covers 1024 consecutive floats -> single channel
    int o = (int)((((size_t)blockIdx.x*1024) >> 16) & 63);
    atomicAdd(&gsum[o], t1);
    atomicAdd(&gsq[o], t2);
  }
}

// ---------------- K4: finalize BN stats into scale/shift ---------------------
__global__ void k_finalize(const float* __restrict__ gsum, const float* __restrict__ gsq,
                           const float* __restrict__ gamma, const float* __restrict__ beta,
                           float* __restrict__ scale, float* __restrict__ shift)
{
  int o = threadIdx.x;
  if (o < OC_){
    float n = (float)NPIX_;
    float mean = gsum[o] / n;
    float var  = gsq[o] / n - mean*mean;          // biased, matches jnp.var
    float sc = gamma[o] * rsqrtf(var + 1e-5f);
    scale[o] = sc;
    shift[o] = beta[o] - mean*sc;
  }
}

// ---------------- K5: BN apply + exact GELU, vectorized x4 -------------------
__global__ __launch_bounds__(256) void k_bn_gelu(
    const float4* __restrict__ outF4,
    const float* __restrict__ scale,
    const float* __restrict__ shift,
    float4* __restrict__ y4)
{
  int i = blockIdx.x*256 + threadIdx.x;           // over NELEM_/4
  int o = (i >> 14) & 63;                         // (4i >> 16) & 63
  float sc = scale[o], sh = shift[o];
  float4 v = outF4[i];
  float4 g;
  float a;
  a = v.x*sc + sh; g.x = 0.5f*a*(1.f + erff(a*0.70710678118654752f));
  a = v.y*sc + sh; g.y = 0.5f*a*(1.f + erff(a*0.70710678118654752f));
  a = v.z*sc + sh; g.z = 0.5f*a*(1.f + erff(a*0.70710678118654752f));
  a = v.w*sc + sh; g.w = 0.5f*a*(1.f + erff(a*0.70710678118654752f));
  y4[i] = g;
}

extern "C" void kernel_launch(void* const* d_in, const int* in_sizes, int n_in,
                              void* d_out, int out_size, void* d_ws, size_t ws_size,
                              hipStream_t stream)
{
  (void)in_sizes; (void)n_in; (void)out_size; (void)ws_size;
  const float* x     = (const float*)d_in[0];
  const float* dw    = (const float*)d_in[1];
  const float* pw    = (const float*)d_in[2];
  const float* w2    = (const float*)d_in[3];
  /* d_in[4] = bias: provably cancels in BN, unused */
  const float* gamma = (const float*)d_in[5];
  const float* beta  = (const float*)d_in[6];

  char* ws = (char*)d_ws;
  float* t     = (float*)(ws);                    // 67,108,864 B
  float* outF  = (float*)(ws + 67108864);         // 67,108,864 B
  float* stats = (float*)(ws + 134217728);        // 1 KiB
  float* gsum  = stats;
  float* gsq   = stats + 64;
  float* scale = stats + 128;
  float* shift = stats + 192;

  hipMemsetAsync(stats, 0, 512, stream);          // zero gsum/gsq

  k_dwconv   <<<NELEM_/256, 256, 0, stream>>>(x, dw, t);
  k_fused    <<<NPIX_/256, 256, 0, stream>>>(x, t, pw, w2, outF);
  k_stats    <<<NELEM_/1024, 256, 0, stream>>>((const float4*)outF, gsum, gsq);
  k_finalize <<<1, 64, 0, stream>>>(gsum, gsq, gamma, beta, scale, shift);
  k_bn_gelu  <<<NELEM_/4/256, 256, 0, stream>>>((const float4*)outF, scale, shift,
                                                (float4*)d_out);
}

// Round 3
// 354.753 us; speedup vs baseline: 2.1006x; 2.1006x over previous
//
#include <hip/hip_runtime.h>

#define B_  4
#define C_  64
#define H_  256
#define W_  256
#define HW_ 65536
#define NPIX_ (B_*HW_)        /* 262144 */
#define NELEM_ (B_*C_*HW_)    /* 16777216 */

#define TS  72      /* bf16 row stride for T/sval, P, W tiles (144B, 16B-aligned, 8-class bank spread) */
#define OMS 194     /* bf16 om row stride (388B; (194/2)%32=1 -> conflict-free strided reads) */
#define OTS 68      /* fp32 outT row stride */

typedef __attribute__((ext_vector_type(8))) short short8;
typedef __attribute__((ext_vector_type(4))) float floatx4;

static __device__ __forceinline__ unsigned short f2bf(float f){
  unsigned u = __float_as_uint(f);
  u += 0x7fff + ((u >> 16) & 1);          // RNE
  return (unsigned short)(u >> 16);
}
static __device__ __forceinline__ float bf2f(unsigned short s){
  return __uint_as_float(((unsigned)s) << 16);
}

// One block = 64 consecutive pixels of one image row (all same batch).
// Pipeline per block: stage pw/w2 + dwconv -> MFMA1 (om, 192ch) -> sample -> MFMA2 -> store + BN partials.
__global__ __launch_bounds__(256, 2) void k_mega(
    const float* __restrict__ x,
    const float* __restrict__ dwW,
    const float* __restrict__ pw,
    const float* __restrict__ w2,
    unsigned short* __restrict__ outB,    // [B][64][HW] bf16
    float* __restrict__ gsum,
    float* __restrict__ gsq)
{
  __shared__ __align__(16) char lds[46080];
  unsigned short* T  = (unsigned short*)lds;            // 64 x TS   (t, later sval)
  unsigned short* Wl = (unsigned short*)(lds + 9216);   // 64 x TS   (w2)
  char*           big = lds + 18432;                    // 27648B region
  unsigned short* P  = (unsigned short*)big;            // 192 x TS  (pw)
  unsigned short* OM = (unsigned short*)big;            // 64 x OMS  (om, overlays P)
  float*          OT = (float*)big;                     // 64 x OTS  (outT, overlays om)
  float*          BS = (float*)Wl;                      // 512 fp32 partials (overlays W)

  int tid  = threadIdx.x;
  int bid  = (blockIdx.x & 7) * 512 + (blockIdx.x >> 3);  // XCD-contiguous tiles
  int b    = bid >> 10;
  int tile = bid & 1023;
  int h    = tile >> 2;
  int w0   = (tile & 3) << 6;
  int p0   = (h << 8) + w0;                // within-image pixel index of tile start

  // ---- phase 0: stage pw -> P, w2 -> Wl (bf16), dwconv -> T --------------
  for (int i = tid; i < 192*64; i += 256){
    int r = i >> 6, c = i & 63;
    P[r*TS + c] = f2bf(pw[i]);
  }
  for (int i = tid; i < 64*64; i += 256){
    int r = i >> 6, c = i & 63;
    Wl[r*TS + c] = f2bf(w2[i]);
  }

  int p  = tid & 63;            // pixel-in-tile
  int cg = tid >> 6;            // channel group
  int wg = w0 + p;              // global column
  {
#pragma unroll
    for (int i = 0; i < 16; ++i){
      int c = cg*16 + i;
      const float* xp = x + ((size_t)(b*C_ + c) << 16);
      const float* wp = dwW + c*9;
      float acc = 0.f;
#pragma unroll
      for (int dy = -1; dy <= 1; ++dy){
        int hy = h + dy;
        if ((unsigned)hy >= (unsigned)H_) continue;
        const float* row = xp + (hy << 8);
#pragma unroll
        for (int dx = -1; dx <= 1; ++dx){
          int wx = wg + dx;
          if ((unsigned)wx >= (unsigned)W_) continue;
          acc += wp[(dy+1)*3 + (dx+1)] * row[wx];
        }
      }
      T[p*TS + c] = f2bf(acc);
    }
  }
  __syncthreads();

  // ---- phase 1: MFMA1  om[p][ch] = sum_c t[p][c] * pw[ch][c] -------------
  int lane = tid & 63, wv = tid >> 6;
  int mrow = lane & 15, q = lane >> 4;
  floatx4 zero4 = {0.f, 0.f, 0.f, 0.f};

  short8 af[4][2];
#pragma unroll
  for (int mt = 0; mt < 4; ++mt)
#pragma unroll
    for (int kb = 0; kb < 2; ++kb)
      af[mt][kb] = *(const short8*)&T[(mt*16 + mrow)*TS + kb*32 + q*8];

  floatx4 acc1[3][4];
#pragma unroll
  for (int nt = 0; nt < 3; ++nt)
#pragma unroll
    for (int mt = 0; mt < 4; ++mt) acc1[nt][mt] = zero4;

#pragma unroll
  for (int nt = 0; nt < 3; ++nt){
    int ch0 = (wv*3 + nt) * 16;
#pragma unroll
    for (int kb = 0; kb < 2; ++kb){
      short8 bf = *(const short8*)&P[(ch0 + mrow)*TS + kb*32 + q*8];
#pragma unroll
      for (int mt = 0; mt < 4; ++mt)
        acc1[nt][mt] = __builtin_amdgcn_mfma_f32_16x16x32_bf16(af[mt][kb], bf, acc1[nt][mt], 0, 0, 0);
    }
  }
  __syncthreads();     // everyone done reading P before om overlays it

  // D layout: col(=ch) = lane&15, row(=p) = (lane>>4)*4 + reg
#pragma unroll
  for (int nt = 0; nt < 3; ++nt){
    int ch = (wv*3 + nt)*16 + mrow;
#pragma unroll
    for (int mt = 0; mt < 4; ++mt)
#pragma unroll
      for (int r = 0; r < 4; ++r)
        OM[(mt*16 + q*4 + r)*OMS + ch] = f2bf(acc1[nt][mt][r]);
  }
  __syncthreads();

  // ---- phase 2: deformable bilinear sampling -> sval (reuses T) ----------
  // channel mapping: sy uses om[2c], sx uses om[2c+1], modulator om[128+c]
  {
    const float* xb = x + ((size_t)(b*C_) << 16);
    float hf = (float)h, wf = (float)wg;
#pragma unroll 4
    for (int i = 0; i < 16; ++i){
      int c = cg*16 + i;
      unsigned pair = *(const unsigned*)&OM[p*OMS + 2*c];
      float oy = bf2f((unsigned short)(pair & 0xffffu));
      float ox = bf2f((unsigned short)(pair >> 16));
      float mm = bf2f(OM[p*OMS + 128 + c]);
      float mod = 2.f / (1.f + __expf(-mm));
      oy = fminf(fmaxf(oy, -64.f), 64.f);
      ox = fminf(fmaxf(ox, -64.f), 64.f);
      float sy = hf + oy, sx = wf + ox;
      float y0f = floorf(sy), x0f = floorf(sx);
      float wy = sy - y0f, wxr = sx - x0f;
      int y0 = (int)y0f, x0 = (int)x0f;
      const float* xc = xb + ((size_t)c << 16);
      bool y0v = ((unsigned)y0     < (unsigned)H_);
      bool y1v = ((unsigned)(y0+1) < (unsigned)H_);
      bool x0v = ((unsigned)x0     < (unsigned)W_);
      bool x1v = ((unsigned)(x0+1) < (unsigned)W_);
      int base0 = (y0 << 8) + x0;
      float v00 = (y0v && x0v) ? xc[base0]        : 0.f;
      float v01 = (y0v && x1v) ? xc[base0 + 1]    : 0.f;
      float v10 = (y1v && x0v) ? xc[base0 + W_]   : 0.f;
      float v11 = (y1v && x1v) ? xc[base0 + W_+1] : 0.f;
      float sres = (1.f-wy)*((1.f-wxr)*v00 + wxr*v01) + wy*((1.f-wxr)*v10 + wxr*v11);
      T[p*TS + c] = f2bf(sres * mod);
    }
  }
  __syncthreads();

  // ---- phase 3: MFMA2  out[p][och] = sum_c sval[p][c] * w2[och][c] -------
  short8 a2[4][2];
#pragma unroll
  for (int mt = 0; mt < 4; ++mt)
#pragma unroll
    for (int kb = 0; kb < 2; ++kb)
      a2[mt][kb] = *(const short8*)&T[(mt*16 + mrow)*TS + kb*32 + q*8];

  int ochB = wv * 16;
  short8 b2[2];
#pragma unroll
  for (int kb = 0; kb < 2; ++kb)
    b2[kb] = *(const short8*)&Wl[(ochB + mrow)*TS + kb*32 + q*8];

  floatx4 acc2[4];
#pragma unroll
  for (int mt = 0; mt < 4; ++mt) acc2[mt] = zero4;
#pragma unroll
  for (int mt = 0; mt < 4; ++mt)
#pragma unroll
    for (int kb = 0; kb < 2; ++kb)
      acc2[mt] = __builtin_amdgcn_mfma_f32_16x16x32_bf16(a2[mt][kb], b2[kb], acc2[mt], 0, 0, 0);
  __syncthreads();   // om region + Wl done being read

  // transpose through LDS: OT[och][p]
  {
    int och = ochB + mrow;
#pragma unroll
    for (int mt = 0; mt < 4; ++mt)
#pragma unroll
      for (int r = 0; r < 4; ++r)
        OT[och*OTS + mt*16 + q*4 + r] = acc2[mt][r];
  }
  __syncthreads();

  // ---- phase 4: coalesced bf16 store + BN partial sums -------------------
  {
    int och = tid >> 2, pg = tid & 3;
    const float* src = &OT[och*OTS + pg*16];
    float s1 = 0.f, s2 = 0.f;
    unsigned pk[8];
#pragma unroll
    for (int k = 0; k < 16; k += 2){
      float a = src[k], bb = src[k+1];
      s1 += a + bb;
      s2 += a*a + bb*bb;
      pk[k >> 1] = (unsigned)f2bf(a) | ((unsigned)f2bf(bb) << 16);
    }
    size_t gaddr = ((size_t)(b*C_ + och) << 16) + p0 + pg*16;
    uint4 u0; u0.x = pk[0]; u0.y = pk[1]; u0.z = pk[2]; u0.w = pk[3];
    uint4 u1; u1.x = pk[4]; u1.y = pk[5]; u1.z = pk[6]; u1.w = pk[7];
    *(uint4*)(outB + gaddr)     = u0;
    *(uint4*)(outB + gaddr + 8) = u1;
    BS[och*4 + pg]       = s1;
    BS[256 + och*4 + pg] = s2;
  }
  __syncthreads();
  if (tid < 64){
    float t1 = BS[tid*4] + BS[tid*4+1] + BS[tid*4+2] + BS[tid*4+3];
    float t2 = BS[256 + tid*4] + BS[256 + tid*4+1] + BS[256 + tid*4+2] + BS[256 + tid*4+3];
    atomicAdd(&gsum[tid], t1);
    atomicAdd(&gsq[tid], t2);
  }
}

// ---------------- finalize BN stats into scale/shift ------------------------
__global__ void k_finalize(const float* __restrict__ gsum, const float* __restrict__ gsq,
                           const float* __restrict__ gamma, const float* __restrict__ beta,
                           float* __restrict__ scale, float* __restrict__ shift)
{
  int o = threadIdx.x;
  if (o < 64){
    float n = (float)NPIX_;
    float mean = gsum[o] / n;
    float var  = gsq[o] / n - mean*mean;          // biased, matches jnp.var
    float sc = gamma[o] * rsqrtf(var + 1e-5f);
    scale[o] = sc;
    shift[o] = beta[o] - mean*sc;
  }
}

// ---------------- BN apply + exact GELU, 8 elems/thread ---------------------
__global__ __launch_bounds__(256) void k_bn_gelu(
    const uint4* __restrict__ outB4,   // 8 bf16
    const float* __restrict__ scale,
    const float* __restrict__ shift,
    float4* __restrict__ y4)
{
  int i = blockIdx.x*256 + threadIdx.x;           // over NELEM_/8
  int och = (i >> 13) & 63;                       // (8i >> 16) & 63
  float sc = scale[och], sh = shift[och];
  uint4 u = outB4[i];
  float e[8];
  e[0] = bf2f((unsigned short)(u.x & 0xffffu)); e[1] = bf2f((unsigned short)(u.x >> 16));
  e[2] = bf2f((unsigned short)(u.y & 0xffffu)); e[3] = bf2f((unsigned short)(u.y >> 16));
  e[4] = bf2f((unsigned short)(u.z & 0xffffu)); e[5] = bf2f((unsigned short)(u.z >> 16));
  e[6] = bf2f((unsigned short)(u.w & 0xffffu)); e[7] = bf2f((unsigned short)(u.w >> 16));
  float4 o0, o1;
  float a;
  a = e[0]*sc + sh; o0.x = 0.5f*a*(1.f + erff(a*0.70710678118654752f));
  a = e[1]*sc + sh; o0.y = 0.5f*a*(1.f + erff(a*0.70710678118654752f));
  a = e[2]*sc + sh; o0.z = 0.5f*a*(1.f + erff(a*0.70710678118654752f));
  a = e[3]*sc + sh; o0.w = 0.5f*a*(1.f + erff(a*0.70710678118654752f));
  a = e[4]*sc + sh; o1.x = 0.5f*a*(1.f + erff(a*0.70710678118654752f));
  a = e[5]*sc + sh; o1.y = 0.5f*a*(1.f + erff(a*0.70710678118654752f));
  a = e[6]*sc + sh; o1.z = 0.5f*a*(1.f + erff(a*0.70710678118654752f));
  a = e[7]*sc + sh; o1.w = 0.5f*a*(1.f + erff(a*0.70710678118654752f));
  y4[2*i]   = o0;
  y4[2*i+1] = o1;
}

extern "C" void kernel_launch(void* const* d_in, const int* in_sizes, int n_in,
                              void* d_out, int out_size, void* d_ws, size_t ws_size,
                              hipStream_t stream)
{
  (void)in_sizes; (void)n_in; (void)out_size; (void)ws_size;
  const float* x     = (const float*)d_in[0];
  const float* dw    = (const float*)d_in[1];
  const float* pw    = (const float*)d_in[2];
  const float* w2    = (const float*)d_in[3];
  /* d_in[4] = bias: cancels exactly in BN (mean-subtracted), unused */
  const float* gamma = (const float*)d_in[5];
  const float* beta  = (const float*)d_in[6];

  char* ws = (char*)d_ws;
  unsigned short* outB  = (unsigned short*)ws;          // 33,554,432 B bf16
  float*          stats = (float*)(ws + 33554432);      // 1 KiB
  float* gsum  = stats;
  float* gsq   = stats + 64;
  float* scale = stats + 128;
  float* shift = stats + 192;

  hipMemsetAsync(stats, 0, 512, stream);                // zero gsum/gsq

  k_mega    <<<NPIX_/64, 256, 0, stream>>>(x, dw, pw, w2, outB, gsum, gsq);
  k_finalize<<<1, 64, 0, stream>>>(gsum, gsq, gamma, beta, scale, shift);
  k_bn_gelu <<<NELEM_/8/256, 256, 0, stream>>>((const uint4*)outB, scale, shift,
                                               (float4*)d_out);
}